// Round 3
// baseline (216.864 us; speedup 1.0000x reference)
//
#include <hip/hip_runtime.h>

// YOLO loss reduction: B=512, 3136 cells/sample, 15 slots/cell, fp32, sum.
//
// R5 fast-math slot-stream 76us. R6 batch-8 reg pipeline 72us (VGPR=60,
// compiler re-serialized). R7 residency fix (1960 blocks, depth-2 reg
// pipeline) 71us, VGPR=20: occupancy 31->53% with ZERO dur change ->
// occupancy is not the limiter; compiler rolls ANY register pipeline back
// to load->vmcnt(0)->compute. VALUBusy 24%, HBM 17%: ~77% of cycles are
// exposed vmcnt stalls (lockstep convoy).
// R8: async-LDS pipeline (T3/T4, m201 precedent) -- container failed twice,
//    no profile; sync ledger re-audited clean (likely infra: prior round
//    showed 1350s npz push).
// R9: R8 resubmitted with the risk surface trimmed: memset restored on the
//    fast path (poison-semantics insurance). Design: global_load_lds
//    width=16 stages o (depth 3, ahead-2) and t (depth 2, ahead-1) into
//    LDS; counted s_waitcnt vmcnt(1) + raw s_barrier per iter (NEVER
//    vmcnt(0) mid-loop). Stages cell-aligned (960 el = 64 cells): slot/
//    wrap/gate indices are pure tid functions (hoisted magic-div VALU),
//    gates read from LDS (no per-iter global gathers). Grid 1792 = 7
//    blocks/CU exact; LDS 19.2 KB; __launch_bounds__(256,7).

#define EPSF 1e-9f
#define LN2F 0.69314718055994530942f

#define KITERS   14
#define STAGE_F4 240                 // 960 floats = 64 cells per stage
#define BLK_F4   (KITERS * STAGE_F4) // 3360 float4s per block
#define FAST_N   (1792 * BLK_F4 * 4) // 24,084,480 floats

__device__ __forceinline__ float bce_of(float ox, float tx) {
    const float l1 = __log2f(ox + EPSF);
    const float l2 = __log2f((1.f - ox) + EPSF);
    return -LN2F * (tx * l1 + (1.f - tx) * l2);
}

// ---------- fast path: grid 1792, 14 cell-aligned stages/block ----------
__global__ __launch_bounds__(256, 7) void yolo_loss_lds(
    const float* __restrict__ o, const float* __restrict__ t,
    float* __restrict__ out_sum)
{
    __shared__ float4 obuf[3][STAGE_F4];   // 11,520 B, depth 3 (ahead-2)
    __shared__ float4 tbuf[2][STAGE_F4];   //  7,680 B, depth 2 (ahead-1)
    __shared__ float  wsum[4];

    const int tid = threadIdx.x;
    const int wid = tid >> 6;
    const float4* o4 = (const float4*)o;
    const float4* t4 = (const float4*)t;
    const unsigned base4 = blockIdx.x * (unsigned)BLK_F4;
    const bool active = tid < STAGE_F4;    // 240 of 256 lanes carry data

    // ---- per-thread slot constants (stage cell-aligned: e = tid*4 in [0,960)) ----
    const unsigned e0 = (unsigned)tid * 4u;
    const unsigned c0 = e0 / 15u;
    const unsigned c3 = (e0 + 3u) / 15u;
    const unsigned s0 = e0 - c0 * 15u;
    const unsigned glo_off = c0 * 15u;     // gate element offset within tile
    const unsigned ghi_off = c3 * 15u;     // always < 960 (c3 <= 63)
    bool is4[4], ksq[4], kz[4], wr[4];
    #pragma unroll
    for (int j = 0; j < 4; ++j) {
        const unsigned s = s0 + (unsigned)j;          // s in [0,17]
        is4[j] = (s == 4u);                           // confidence -> BCE
        ksq[j] = (s == 2u) | (s == 3u) | (s == 17u);  // w/h -> sqrt term
        kz[j]  = (s == 1u) | (s == 14u) | (s == 16u); // zeroed slots
        wr[j]  = (s >= 15u);                          // belongs to next cell
    }

    // ---- async stage issue (wave-uniform LDS base + lane*16; linear layout) ----
    auto stage_o = [&](int kk, int bo) {
        if (active)
            __builtin_amdgcn_global_load_lds(
                (const void*)(o4 + base4 + (unsigned)kk * STAGE_F4 + (unsigned)tid),
                (void*)&obuf[bo][wid * 64], 16, 0, 0);
    };
    auto stage_t = [&](int kk, int bt) {
        if (active)
            __builtin_amdgcn_global_load_lds(
                (const void*)(t4 + base4 + (unsigned)kk * STAGE_F4 + (unsigned)tid),
                (void*)&tbuf[bt][wid * 64], 16, 0, 0);
    };

    // prologue: queue {o0, t0, o1}  (3 outstanding)
    stage_o(0, 0);
    stage_t(0, 0);
    stage_o(1, 1);

    float acc = 0.f;
    #pragma unroll
    for (int k = 0; k < KITERS; ++k) {
        // wait for stage k (leave next o in flight); drain only on last iter
        __builtin_amdgcn_sched_barrier(0);
        if (k < KITERS - 1) asm volatile("s_waitcnt vmcnt(1)" ::: "memory");
        else                asm volatile("s_waitcnt vmcnt(0)" ::: "memory");
        __builtin_amdgcn_s_barrier();          // cross-wave gate reads need this
        __builtin_amdgcn_sched_barrier(0);

        // issue ahead: t first, then o (keeps vmcnt(1) semantics exact)
        if (k + 1 < KITERS) stage_t(k + 1, (k + 1) & 1);
        if (k + 2 < KITERS) stage_o(k + 2, (k + 2) % 3);

        if (active) {
            const float4 ov = obuf[k % 3][tid];
            const float4 tv = tbuf[k & 1][tid];
            const float* ob_f = (const float*)&obuf[k % 3][0];
            const float glo = ob_f[glo_off];
            const float ghi = ob_f[ghi_off];

            const float oe[4] = {ov.x, ov.y, ov.z, ov.w};
            const float te[4] = {tv.x, tv.y, tv.z, tv.w};

            // confidence element select (precomputed masks) -> 1 BCE per float4
            float oc = oe[3], tc = te[3];
            #pragma unroll
            for (int j = 2; j >= 0; --j) { oc = is4[j] ? oe[j] : oc; tc = is4[j] ? te[j] : tc; }
            const float bce = bce_of(oc, tc);  // garbage-safe: inputs in (0,1)

            #pragma unroll
            for (int j = 0; j < 4; ++j) {
                const float gate = wr[j] ? ghi : glo;
                const float ox = oe[j], tx = te[j];
                const float d  = ox - tx;
                const float sq = d * d;
                const float s23 = (ox + tx) - 2.f * __builtin_amdgcn_sqrtf(ox * tx);
                float c = ksq[j] ? s23 : sq;
                c = is4[j] ? bce : c;
                c = kz[j] ? 0.f : c;
                c = (gate != 0.f) ? c : 0.f;
                acc += c;
            }
        }
    }

    #pragma unroll
    for (int off = 32; off; off >>= 1) acc += __shfl_down(acc, off, 64);
    if ((tid & 63) == 0) wsum[wid] = acc;
    __syncthreads();
    if (tid == 0) atomicAdd(out_sum, wsum[0] + wsum[1] + wsum[2] + wsum[3]);
}

// ---------- generic fallback (any n): R5-style guarded grid-stride ----------
__global__ __launch_bounds__(256) void yolo_loss_generic(
    const float* __restrict__ o, const float* __restrict__ t,
    float* __restrict__ out_sum, int n4, int n)
{
    const int tid = threadIdx.x;
    const int stride = gridDim.x * 256;
    const float4* o4 = (const float4*)o;
    const float4* t4 = (const float4*)t;
    float acc = 0.f;

    for (int i = blockIdx.x * 256 + tid; i < n4; i += stride) {
        const float4 ov = o4[i];
        const float4 tv = t4[i];
        const unsigned e0 = (unsigned)i * 4u;
        const unsigned c0 = e0 / 15u;
        const unsigned c3 = (e0 + 3u) / 15u;
        const unsigned s0 = e0 - c0 * 15u;
        const float glo = o[c0 * 15u], ghi = o[c3 * 15u];
        const float oe[4] = {ov.x, ov.y, ov.z, ov.w};
        const float te[4] = {tv.x, tv.y, tv.z, tv.w};
        #pragma unroll
        for (int j = 0; j < 4; ++j) {
            unsigned s = s0 + (unsigned)j;
            const bool wrap = s >= 15u;
            s = wrap ? s - 15u : s;
            const float gate = wrap ? ghi : glo;
            const float ox = oe[j], tx = te[j];
            const float d = ox - tx;
            const float sq = d * d;
            const float s23 = (ox + tx) - 2.f * __builtin_amdgcn_sqrtf(ox * tx);
            float c = ((s == 2u) | (s == 3u)) ? s23 : sq;
            c = (s == 4u) ? bce_of(ox, tx) : c;
            c = ((s == 1u) | (s == 14u)) ? 0.f : c;
            c = (gate != 0.f) ? c : 0.f;
            acc += c;
        }
    }
    const int tail0 = n4 * 4;
    if (blockIdx.x == 0 && tid < n - tail0) {
        const unsigned e = (unsigned)(tail0 + tid);
        const unsigned cell = e / 15u;
        const unsigned s = e - cell * 15u;
        const float gate = o[cell * 15u];
        const float ox = o[e], tx = t[e];
        const float d = ox - tx;
        float c = d * d;
        c = ((s == 2u) | (s == 3u)) ? (ox + tx) - 2.f * __builtin_amdgcn_sqrtf(ox * tx) : c;
        c = (s == 4u) ? bce_of(ox, tx) : c;
        c = ((s == 1u) | (s == 14u)) ? 0.f : c;
        c = (gate != 0.f) ? c : 0.f;
        acc += c;
    }
    #pragma unroll
    for (int off = 32; off; off >>= 1) acc += __shfl_down(acc, off, 64);
    __shared__ float wsum[4];
    if ((tid & 63) == 0) wsum[tid >> 6] = acc;
    __syncthreads();
    if (tid == 0) atomicAdd(out_sum, wsum[0] + wsum[1] + wsum[2] + wsum[3]);
}

extern "C" void kernel_launch(void* const* d_in, const int* in_sizes, int n_in,
                              void* d_out, int out_size, void* d_ws, size_t ws_size,
                              hipStream_t stream) {
    const float* o = (const float*)d_in[0];
    const float* t = (const float*)d_in[1];
    float* out = (float*)d_out;
    const int n = in_sizes[0];

    // d_out is poisoned 0xAA before every timed replay -> zero it on-stream.
    hipMemsetAsync(out, 0, sizeof(float), stream);

    if (n == FAST_N) {
        yolo_loss_lds<<<1792, 256, 0, stream>>>(o, t, out);
    } else {
        yolo_loss_generic<<<2940, 256, 0, stream>>>(o, t, out, n / 4, n);
    }
}

// Round 4
// 208.361 us; speedup vs baseline: 1.0408x; 1.0408x over previous
//
#include <hip/hip_runtime.h>

// YOLO loss reduction: B=512, 3136 cells/sample, 15 slots/cell, fp32, sum.
//
// R5 slot-stream 76us. R6 batch-8 reg pipeline 72us (VGPR=60: compiler
// re-serialized). R7 depth-2 reg pipeline + residency fix 71us (VGPR=20:
// fully collapsed; occupancy 31->53% with zero dur change). R9 async-LDS
// pipeline (ahead-1 t, per-iter s_barrier, 240/256 lanes) REGRESSED to
// 86us, VALUBusy 14%: barrier lockstep + too-shallow prefetch cut MLP.
// [R0's "dispatch-124 = L3-resident, same time" claim retracted: FETCH was
// NaN = other counter group, not a real zero-HBM run.]
// Triangulation: ~1850 cy per wave-iteration, ~440 cy VALU -> ~75% exposed
// vmem latency at ~2 loads in flight/wave. Compiler collapses any plain-HIP
// register pipeline; LDS route needs barriers (convoy).
// R10: inline-asm register pipeline the compiler CANNOT collapse.
//    Depth-4 ring, ahead-3: per iter issue {o dwordx4, t dwordx4, 2 gate
//    dwords} via asm volatile global_load_*, consume after counted
//    s_waitcnt vmcnt(4*min(3,rem)) + sched_barrier(0) (rule-18 fence).
//    16 loads in flight/wave steady-state. No LDS, no barriers, waves
//    fully independent. Grid 1470 x 256thr x 16 iters = n4 exactly;
//    <=6 blk/CU -> all resident. launch_bounds(256,6): 85-VGPR cap vs
//    ~68 live -> no spill.

#define EPSF 1e-9f
#define LN2F 0.69314718055994530942f

#define GRID   1470
#define ITERS  16
#define TSTR   (GRID * 256)            // 376,320 float4 stride per iter
#define FAST_N (TSTR * ITERS * 4)      // 24,084,480 floats

typedef float f32x4 __attribute__((ext_vector_type(4)));

__device__ __forceinline__ f32x4 ldg4(const f32x4* p) {
    f32x4 r;
    asm volatile("global_load_dwordx4 %0, %1, off" : "=v"(r) : "v"(p));
    return r;
}
__device__ __forceinline__ float ldg1(const float* p) {
    float r;
    asm volatile("global_load_dword %0, %1, off" : "=v"(r) : "v"(p));
    return r;
}

__device__ __forceinline__ float bce_of(float ox, float tx) {
    const float l1 = __log2f(ox + EPSF);
    const float l2 = __log2f((1.f - ox) + EPSF);
    return -LN2F * (tx * l1 + (1.f - tx) * l2);
}

// ---------- fast path: asm-pipelined, grid*256*16 == n4 exactly ----------
__global__ __launch_bounds__(256, 6) void yolo_loss_pipe(
    const float* __restrict__ o, const float* __restrict__ t,
    float* __restrict__ out_sum)
{
    const int tid = threadIdx.x;
    const unsigned idx = blockIdx.x * 256u + (unsigned)tid;
    const f32x4* o4 = (const f32x4*)o;
    const f32x4* t4 = (const f32x4*)t;

    // depth-4 ring: asm outputs are forced live -> compiler cannot collapse
    f32x4 ob[4], tb[4];
    float gl[4], gh[4];
    unsigned sl[4];

    auto issue = [&](int kk) {            // kk is compile-time (full unroll)
        const unsigned i  = idx + (unsigned)kk * (unsigned)TSTR;
        const unsigned e0 = i * 4u;
        const unsigned c0 = e0 / 15u;     // magic-mul div
        const unsigned c3 = (e0 + 3u) / 15u;
        sl[kk & 3] = e0 - c0 * 15u;
        ob[kk & 3] = ldg4(o4 + i);
        tb[kk & 3] = ldg4(t4 + i);
        gl[kk & 3] = ldg1(o + c0 * 15u);  // gate gathers: L1-hot
        gh[kk & 3] = ldg1(o + c3 * 15u);
    };

    // prologue: 3 iterations in flight (12 loads)
    issue(0); issue(1); issue(2);

    float acc = 0.f;
    #pragma unroll
    for (int k = 0; k < ITERS; ++k) {
        // issue-first (depth-4 ring: slot (k+3)&3 != k&3, no WAR with consume)
        if (k + 3 < ITERS) issue(k + 3);

        // counted wait: retire exactly iter k's 4 loads, keep the rest in flight
        const int ahead = (ITERS - 1 - k) < 3 ? (ITERS - 1 - k) : 3;
        if (ahead == 3)      asm volatile("s_waitcnt vmcnt(12)" ::: "memory");
        else if (ahead == 2) asm volatile("s_waitcnt vmcnt(8)"  ::: "memory");
        else if (ahead == 1) asm volatile("s_waitcnt vmcnt(4)"  ::: "memory");
        else                 asm volatile("s_waitcnt vmcnt(0)"  ::: "memory");
        __builtin_amdgcn_sched_barrier(0);  // rule-18: no consume hoists above wait

        // ---- consume iter k ----
        const unsigned s0 = sl[k & 3];
        const float glo = gl[k & 3], ghi = gh[k & 3];
        const f32x4 ov = ob[k & 3], tv = tb[k & 3];
        const float oe[4] = {ov.x, ov.y, ov.z, ov.w};
        const float te[4] = {tv.x, tv.y, tv.z, tv.w};

        // slot-4 (confidence) element: at most one per float4 -> 1 BCE
        bool is4[4];
        #pragma unroll
        for (int j = 0; j < 4; ++j) {
            const unsigned s = s0 + (unsigned)j;
            is4[j] = (s == 4u) | (s == 19u);
        }
        float oc = oe[3], tc = te[3];
        #pragma unroll
        for (int j = 2; j >= 0; --j) { oc = is4[j] ? oe[j] : oc; tc = is4[j] ? te[j] : tc; }
        const float bce = bce_of(oc, tc);   // garbage-safe: inputs in (0,1)

        #pragma unroll
        for (int j = 0; j < 4; ++j) {
            unsigned s = s0 + (unsigned)j;
            const bool wrap = s >= 15u;
            s = wrap ? s - 15u : s;
            const float gate = wrap ? ghi : glo;
            const float ox = oe[j], tx = te[j];
            const float d  = ox - tx;
            const float sq = d * d;
            const float s23 = (ox + tx) - 2.f * __builtin_amdgcn_sqrtf(ox * tx);
            float c = ((s == 2u) | (s == 3u)) ? s23 : sq;
            c = is4[j] ? bce : c;
            c = ((s == 1u) | (s == 14u)) ? 0.f : c;
            c = (gate != 0.f) ? c : 0.f;
            acc += c;
        }
    }

    #pragma unroll
    for (int off = 32; off; off >>= 1) acc += __shfl_down(acc, off, 64);
    __shared__ float wsum[4];
    if ((tid & 63) == 0) wsum[tid >> 6] = acc;
    __syncthreads();
    if (tid == 0) atomicAdd(out_sum, wsum[0] + wsum[1] + wsum[2] + wsum[3]);
}

// ---------- generic fallback (any n): R5-style guarded grid-stride ----------
__global__ __launch_bounds__(256) void yolo_loss_generic(
    const float* __restrict__ o, const float* __restrict__ t,
    float* __restrict__ out_sum, int n4, int n)
{
    const int tid = threadIdx.x;
    const int stride = gridDim.x * 256;
    const float4* o4 = (const float4*)o;
    const float4* t4 = (const float4*)t;
    float acc = 0.f;

    for (int i = blockIdx.x * 256 + tid; i < n4; i += stride) {
        const float4 ov = o4[i];
        const float4 tv = t4[i];
        const unsigned e0 = (unsigned)i * 4u;
        const unsigned c0 = e0 / 15u;
        const unsigned c3 = (e0 + 3u) / 15u;
        const unsigned s0 = e0 - c0 * 15u;
        const float glo = o[c0 * 15u], ghi = o[c3 * 15u];
        const float oe[4] = {ov.x, ov.y, ov.z, ov.w};
        const float te[4] = {tv.x, tv.y, tv.z, tv.w};
        #pragma unroll
        for (int j = 0; j < 4; ++j) {
            unsigned s = s0 + (unsigned)j;
            const bool wrap = s >= 15u;
            s = wrap ? s - 15u : s;
            const float gate = wrap ? ghi : glo;
            const float ox = oe[j], tx = te[j];
            const float d = ox - tx;
            const float sq = d * d;
            const float s23 = (ox + tx) - 2.f * __builtin_amdgcn_sqrtf(ox * tx);
            float c = ((s == 2u) | (s == 3u)) ? s23 : sq;
            c = (s == 4u) ? bce_of(ox, tx) : c;
            c = ((s == 1u) | (s == 14u)) ? 0.f : c;
            c = (gate != 0.f) ? c : 0.f;
            acc += c;
        }
    }
    const int tail0 = n4 * 4;
    if (blockIdx.x == 0 && tid < n - tail0) {
        const unsigned e = (unsigned)(tail0 + tid);
        const unsigned cell = e / 15u;
        const unsigned s = e - cell * 15u;
        const float gate = o[cell * 15u];
        const float ox = o[e], tx = t[e];
        const float d = ox - tx;
        float c = d * d;
        c = ((s == 2u) | (s == 3u)) ? (ox + tx) - 2.f * __builtin_amdgcn_sqrtf(ox * tx) : c;
        c = (s == 4u) ? bce_of(ox, tx) : c;
        c = ((s == 1u) | (s == 14u)) ? 0.f : c;
        c = (gate != 0.f) ? c : 0.f;
        acc += c;
    }
    #pragma unroll
    for (int off = 32; off; off >>= 1) acc += __shfl_down(acc, off, 64);
    __shared__ float wsum[4];
    if ((tid & 63) == 0) wsum[tid >> 6] = acc;
    __syncthreads();
    if (tid == 0) atomicAdd(out_sum, wsum[0] + wsum[1] + wsum[2] + wsum[3]);
}

extern "C" void kernel_launch(void* const* d_in, const int* in_sizes, int n_in,
                              void* d_out, int out_size, void* d_ws, size_t ws_size,
                              hipStream_t stream) {
    const float* o = (const float*)d_in[0];
    const float* t = (const float*)d_in[1];
    float* out = (float*)d_out;
    const int n = in_sizes[0];

    // d_out is poisoned 0xAA before every timed replay -> zero it on-stream.
    hipMemsetAsync(out, 0, sizeof(float), stream);

    if (n == FAST_N) {
        yolo_loss_pipe<<<GRID, 256, 0, stream>>>(o, t, out);
    } else {
        yolo_loss_generic<<<2940, 256, 0, stream>>>(o, t, out, n / 4, n);
    }
}